// Round 17
// baseline (173.638 us; speedup 1.0000x reference)
//
#include <hip/hip_runtime.h>
#include <cstdint>
#include <cstddef>

#define Bn 64
#define Tn 2048
#define Un 512
#define QSn 512
#define MSn 512
#define TCH 64
#define NCH 32   // chunks per batch = Tn/TCH
#define NKT 16   // K-tiles: 512 / 32

using f32x16 = __attribute__((ext_vector_type(16))) float;
using bf16x8 = __attribute__((ext_vector_type(8))) short;

__device__ __forceinline__ unsigned short f2bf(float x) {
    unsigned int u = __float_as_uint(x);
    u += 0x7FFFu + ((u >> 16) & 1u);
    return (unsigned short)(u >> 16);
}

__device__ __forceinline__ unsigned int pk2bf(float lo, float hi) {
    unsigned int r;
    asm("v_cvt_pk_bf16_f32 %0, %1, %2" : "=v"(r) : "v"(lo), "v"(hi));
    return r;
}

__device__ __forceinline__ float tanh_fast(float x) {
    float e = exp2f(x * 2.885390043258667f);   // e^{2x}
    return 1.f - 2.f * __builtin_amdgcn_rcpf(e + 1.f);
}

// async global->LDS, 16B per lane; LDS dest = wave-uniform base + lane*16
#define GLOAD(G, L) __builtin_amdgcn_global_load_lds( \
    (const __attribute__((address_space(1))) void*)(G), \
    (__attribute__((address_space(3))) void*)(L), 16, 0, 0)

#define SB() __builtin_amdgcn_sched_barrier(0)

// ---------------- Wm f32 -> bf16 pre-convert ----------------
__global__ __launch_bounds__(256) void cvt_kernel(const float* __restrict__ src,
                                                  unsigned short* __restrict__ dst) {
    int i = blockIdx.x * 256 + threadIdx.x;  // one float4 per thread
    float4 v = *(const float4*)(src + (size_t)i * 4);
    ushort4 h = { f2bf(v.x), f2bf(v.y), f2bf(v.z), f2bf(v.w) };
    *(ushort4*)&dst[(size_t)i * 4] = h;
}

// ---------------- pq = query @ Wq^T : [B,U] ----------------
__global__ __launch_bounds__(128) void pq_kernel(const float* __restrict__ query,
                                                 const float* __restrict__ Wq,
                                                 float* __restrict__ pq) {
    __shared__ float ql[QSn];
    const int b = blockIdx.x;
    const int quad = blockIdx.y;
    const int tid = threadIdx.x;
    for (int i = tid; i < QSn; i += 128) ql[i] = query[(size_t)b * QSn + i];
    __syncthreads();
    const int u = quad * 128 + tid;
    const float* w = Wq + (size_t)u * QSn;
    float a0 = 0.f, a1 = 0.f;
    #pragma unroll 4
    for (int k = 0; k < QSn; k += 8) {
        float4 w0 = *(const float4*)(w + k);
        float4 w1 = *(const float4*)(w + k + 4);
        float4 q0 = *(const float4*)(ql + k);
        float4 q1 = *(const float4*)(ql + k + 4);
        a0 += w0.x * q0.x + w0.y * q0.y + w0.z * q0.z + w0.w * q0.w;
        a1 += w1.x * q1.x + w1.y * q1.y + w1.z * q1.z + w1.w * q1.w;
    }
    pq[(size_t)b * Un + u] = a0 + a1;
}

// ---------------- fused score+softmax+context (v17: A depth-2) --------------
// R16 verbatim except the A pipeline is now DEPTH-2:
//  head(kt): issue B(kt+1) GLOADs FIRST, then A(kt+2) flat -> reg slot (kt&1).
//  FIFO at kt's wait: [B(kt)x4, A(kt+1), B(kt+1)x4, A(kt+2)] -> vmcnt(6)
//  drains exactly B(kt) and LEAVES A(kt+1) in flight. Tail cvt of A(kt+1)
//  (slot (kt+1)&1, loaded a full kt earlier ~800+cy slack) uses the
//  COMPILER's auto-wait (register dependency - no hand count, no R12 class).
//  Tails: kt=14 -> vmcnt(5); kt=15 -> vmcnt(0). Prologue order pqwa,A0,B0,A1
//  makes kt=0 identical to steady state.
__global__ __launch_bounds__(512, 4) void fused_kernel(const float* __restrict__ keys,
                                                       const unsigned short* __restrict__ WmB,
                                                       const float* __restrict__ pq,
                                                       const float* __restrict__ Wa,
                                                       float* __restrict__ score_out,
                                                       float* __restrict__ pm,
                                                       float* __restrict__ pl,
                                                       float* __restrict__ pctx) {
    __shared__ __align__(16) unsigned short Ah[2][TCH * 32];    // 8 KB
    __shared__ __align__(16) unsigned short Bh[2][512 * 32];    // 64 KB
    __shared__ float sc_lds[8][TCH];                            // 2 KB
    __shared__ float stot[TCH];
    __shared__ float wexp[TCH];

    const int tid = threadIdx.x;
    const int lane = tid & 63;
    const int w = tid >> 6;
    const int lc = lane & 31;
    const int l5 = lane >> 5;
    const int b = blockIdx.y;
    const int chunk = blockIdx.x;
    const int t0 = chunk * TCH;

    // ---- A staging: ALL 512 threads, 1 float4 each (row ar, k-quad kq)
    const int ar = tid >> 3;          // 0..63
    const int kq = tid & 7;           // 4 f32 at k = kq*4
    const int awof = (ar >> 1) * 64 +
                     (((((kq >> 1) << 1) | (ar & 1)) ^ ((ar >> 1) & 7)) * 8) +
                     (kq & 1) * 4;
    const float* gA = keys + ((size_t)b * Tn + t0 + ar) * MSn + kq * 4;

    // ---- B staging source (R11/R15-verbatim zero-conflict swizzle)
    const int bg = (lane & 7) ^ ((lane >> 3) & 7);
    const unsigned short* gBw = WmB +
        (size_t)(w * 64 + (((lane >> 3) << 1) | (bg & 1))) * MSn + (bg >> 1) * 8;

    #define STAGE_B(KT, BUF) do { \
        const unsigned short* gb_ = gBw + (KT) * 32; \
        char* bD_ = (char*)&Bh[BUF][0] + w * 4096; \
        GLOAD(gb_,                    bD_); \
        GLOAD(gb_ + (size_t)16 * MSn, bD_ + 1024); \
        GLOAD(gb_ + (size_t)32 * MSn, bD_ + 2048); \
        GLOAD(gb_ + (size_t)48 * MSn, bD_ + 3072); } while (0)

    f32x16 acc[2][2];
    #pragma unroll
    for (int mf = 0; mf < 2; ++mf)
        #pragma unroll
        for (int nf = 0; nf < 2; ++nf)
            #pragma unroll
            for (int r = 0; r < 16; ++r) acc[mf][nf][r] = 0.f;

    float4 pA0, pA1;   // A depth-2 reg slots: A(j) lives in slot (j&1)

    // ---- prologue: pq/Wa regs; A(0); B(0); A(1)->slot1; cvt+write A(0)
    float pqv[2], wav[2];
    #pragma unroll
    for (int nf = 0; nf < 2; ++nf) {
        int u = w * 64 + nf * 32 + lc;
        pqv[nf] = pq[(size_t)b * Un + u];
        wav[nf] = Wa[u];
    }
    SB();
    {
        float4 p = *(const float4*)(gA);
        SB();
        STAGE_B(0, 0);
        SB();
        pA1 = *(const float4*)(gA + 32);
        SB();
        uint2 h;
        h.x = pk2bf(p.x, p.y);     // compiler auto-waits A(0); B(0)+A(1) stay out
        h.y = pk2bf(p.z, p.w);
        *(uint2*)&Ah[0][awof] = h;
    }

    #pragma unroll
    for (int kt = 0; kt < NKT; ++kt) {
        // head: B(kt+1) FIRST, then A(kt+2) -> slot (kt&1)
        if (kt < NKT - 1) {
            STAGE_B(kt + 1, (kt + 1) & 1);
            SB();
        }
        if (kt < NKT - 2) {
            if ((kt & 1) == 0) pA0 = *(const float4*)(gA + (kt + 2) * 32);
            else               pA1 = *(const float4*)(gA + (kt + 2) * 32);
            SB();
        }

        // counted wait: drain exactly B(kt); A(kt+1) stays in flight
        if (kt < NKT - 2) {
            asm volatile("s_waitcnt vmcnt(6) lgkmcnt(0)" ::: "memory");
        } else if (kt == NKT - 2) {
            asm volatile("s_waitcnt vmcnt(5) lgkmcnt(0)" ::: "memory");
        } else {
            asm volatile("s_waitcnt vmcnt(0) lgkmcnt(0)" ::: "memory");
        }
        __builtin_amdgcn_s_barrier();   // Ah[kt&1] visible; no vm drain
        SB();

        // ---- MFMA(kt): Ah[kt&1] shared, Bh[kt&1] wave-private rows
        {
            const unsigned short* lA = &Ah[kt & 1][0];
            const unsigned short* lB = &Bh[kt & 1][0];
            #pragma unroll
            for (int ks = 0; ks < 2; ++ks) {
                bf16x8 af[2], bfr[2];
                #pragma unroll
                for (int mf = 0; mf < 2; ++mf) {
                    int r = mf * 32 + lc;
                    int gp = (((ks * 2 + l5) << 1) | (r & 1)) ^ ((r >> 1) & 7);
                    af[mf] = *(const bf16x8*)&lA[(r >> 1) * 64 + gp * 8];
                }
                #pragma unroll
                for (int nf = 0; nf < 2; ++nf) {
                    int ru = w * 64 + nf * 32 + lc;
                    int gp = (((ks * 2 + l5) << 1) | (ru & 1)) ^ ((ru >> 1) & 7);
                    bfr[nf] = *(const bf16x8*)&lB[(ru >> 1) * 64 + gp * 8];
                }
                #pragma unroll
                for (int mf = 0; mf < 2; ++mf)
                    #pragma unroll
                    for (int nf = 0; nf < 2; ++nf)
                        acc[mf][nf] = __builtin_amdgcn_mfma_f32_32x32x16_bf16(
                            af[mf], bfr[nf], acc[mf][nf], 0, 0, 0);
            }
        }
        SB();

        // tail: cvt + write A(kt+1) from slot (kt+1)&1 (issued one full kt
        // ago; compiler auto-waits its load - wave-local, after the barrier)
        if (kt < NKT - 1) {
            float4 p = (((kt + 1) & 1) == 0) ? pA0 : pA1;
            uint2 h;
            h.x = pk2bf(p.x, p.y);
            h.y = pk2bf(p.z, p.w);
            *(uint2*)&Ah[(kt + 1) & 1][awof] = h;
        }
    }
    #undef STAGE_B

    // ---- epilogue: score = sum_u tanh(vals + pq[u]) * Wa[u]
    // C layout: col(u)=lc, row(t) = mf*32 + (r&3) + 8*(r>>2) + 4*l5
    #pragma unroll
    for (int mf = 0; mf < 2; ++mf) {
        #pragma unroll
        for (int r = 0; r < 16; ++r) {
            float s = tanh_fast(acc[mf][0][r] + pqv[0]) * wav[0]
                    + tanh_fast(acc[mf][1][r] + pqv[1]) * wav[1];
            s += __shfl_xor(s, 16);
            s += __shfl_xor(s, 8);
            s += __shfl_xor(s, 4);
            s += __shfl_xor(s, 2);
            s += __shfl_xor(s, 1);
            if (lc == 0)
                sc_lds[w][mf * 32 + (r & 3) + 8 * (r >> 2) + 4 * l5] = s;
        }
    }
    __syncthreads();
    if (tid < TCH) {
        float v = ((sc_lds[0][tid] + sc_lds[1][tid]) + (sc_lds[2][tid] + sc_lds[3][tid]))
                + ((sc_lds[4][tid] + sc_lds[5][tid]) + (sc_lds[6][tid] + sc_lds[7][tid]));
        stot[tid] = v;
        score_out[(size_t)b * Tn + t0 + tid] = v;
    }
    __syncthreads();

    // ---- chunk softmax partials on wave 0
    if (tid < 64) {
        float v = stot[tid];
        float mx = v;
        #pragma unroll
        for (int off = 32; off; off >>= 1) mx = fmaxf(mx, __shfl_xor(mx, off));
        float e = __expf(v - mx);
        wexp[tid] = e;
        float sum = e;
        #pragma unroll
        for (int off = 32; off; off >>= 1) sum += __shfl_xor(sum, off);
        if (tid == 0) {
            pm[b * NCH + chunk] = mx;
            pl[b * NCH + chunk] = sum;
        }
    }
    __syncthreads();

    // ---- ctx partial: thread owns 1 m-col; keys rows re-read (L2/L3-hot)
    const float* kp = keys + ((size_t)b * Tn + t0) * MSn + tid;
    float cx = 0.f;
    #pragma unroll 8
    for (int t = 0; t < TCH; ++t)
        cx += wexp[t] * kp[(size_t)t * MSn];
    pctx[((size_t)(b * NCH + chunk)) * MSn + tid] = cx;
}

// ---------------- merge chunk partials -> total_context ----------------
__global__ __launch_bounds__(512) void merge_kernel(const float* __restrict__ pm,
                                                    const float* __restrict__ pl,
                                                    const float* __restrict__ pctx,
                                                    float* __restrict__ ctx) {
    __shared__ float sm[NCH], sl[NCH];
    const int b = blockIdx.x, tid = threadIdx.x;
    if (tid < NCH) {
        sm[tid] = pm[b * NCH + tid];
        sl[tid] = pl[b * NCH + tid];
    }
    __syncthreads();
    float M = -1e30f;
    #pragma unroll
    for (int c = 0; c < NCH; ++c) M = fmaxf(M, sm[c]);
    float L = 0.f;
    #pragma unroll
    for (int c = 0; c < NCH; ++c) L += sl[c] * __expf(sm[c] - M);
    const float inv = 1.f / L;
    float acc = 0.f;
    #pragma unroll
    for (int c = 0; c < NCH; ++c)
        acc += __expf(sm[c] - M) * pctx[((size_t)(b * NCH + c)) * MSn + tid];
    ctx[(size_t)b * MSn + tid] = acc * inv;
}

extern "C" void kernel_launch(void* const* d_in, const int* in_sizes, int n_in,
                              void* d_out, int out_size, void* d_ws, size_t ws_size,
                              hipStream_t stream) {
    const float* query = (const float*)d_in[0];
    const float* keys  = (const float*)d_in[1];
    const float* Wq    = (const float*)d_in[2];
    const float* Wm    = (const float*)d_in[3];
    const float* Wa    = (const float*)d_in[4];

    float* ctx_out   = (float*)d_out;                    // [64][512]
    float* score_out = (float*)d_out + (size_t)Bn * MSn; // [64][2048]

    char* ws = (char*)d_ws;
    float* ws_pq   = (float*)(ws);                       // 128 KB
    unsigned short* ws_wmbf = (unsigned short*)(ws + 131072);  // 512 KB
    float* ws_pm   = (float*)(ws + 655360);              // 8 KB
    float* ws_pl   = (float*)(ws + 663552);              // 8 KB
    float* ws_pctx = (float*)(ws + 671744);              // 4 MB [64][32][512]

    cvt_kernel<<<(Un * MSn / 4) / 256, 256, 0, stream>>>(Wm, ws_wmbf);
    pq_kernel<<<dim3(Bn, 4), 128, 0, stream>>>(query, Wq, ws_pq);
    fused_kernel<<<dim3(NCH, Bn), 512, 0, stream>>>(keys, ws_wmbf, ws_pq, Wa,
                                                    score_out, ws_pm, ws_pl, ws_pctx);
    merge_kernel<<<Bn, 512, 0, stream>>>(ws_pm, ws_pl, ws_pctx, ctx_out);
}